// Round 1
// baseline (1008.476 us; speedup 1.0000x reference)
//
#include <hip/hip_runtime.h>
#include <hip/hip_bf16.h>

// RGCN 2-layer forward, MI355X.
// out = sigmoid( L2( relu( L1(x) ) ) ),
// L(x) = x@root + bias + sum_r meanagg_r(x @ W_r)
//
// Strategy v1: transform-then-scatter with per-edge 1/count scaling.
//   count[dst*16+r]  (atomics)
//   XR[r] = X @ W[r] (fp32 register-tiled GEMM, K=64)
//   for each edge: out[dst] += XR[type][src] / count[dst][type]  (vector f32 atomics)

#define NN 100000
#define EE 1600000
#define NREL 16

// ---------------- count kernel ----------------
__global__ __launch_bounds__(256) void count_k(const int* __restrict__ ei,
                                               const int* __restrict__ et,
                                               unsigned* __restrict__ C) {
  long i = (long)blockIdx.x * blockDim.x + threadIdx.x;
  long stride = (long)gridDim.x * blockDim.x;
  for (; i < EE; i += stride) {
    int dst = ei[EE + i];
    int t = et[i];
    atomicAdd(&C[(long)dst * NREL + t], 1u);
  }
}

// ---------------- GEMM kernel: OUT[rel][n][DOUT] = act(A[n][64]) @ B[rel][64][DOUT] (+bias) ----------------
// A staged once (transposed) in LDS per block, reused for all nrel relations.
template <int DOUT, bool RELU>
__global__ __launch_bounds__(256) void gemm_k(const float* __restrict__ A,
                                              const float* __restrict__ B,
                                              const float* __restrict__ bias,
                                              float* __restrict__ OUT, int nrel) {
  __shared__ float xT[64][64];     // [k][row]
  __shared__ float Wl[64 * DOUT];  // [k][col]
  const int tid = threadIdx.x;
  const long row0 = (long)blockIdx.x * 64;

  // stage A tile transposed: lane -> row (bank-conflict-free scalar writes)
#pragma unroll
  for (int i = 0; i < 4; ++i) {
    int idx = tid + i * 256;  // 0..1023
    int r = idx & 63, kq = idx >> 6;
    float4 v = make_float4(0.f, 0.f, 0.f, 0.f);
    long grow = row0 + r;
    if (grow < (long)NN) {
      v = *reinterpret_cast<const float4*>(A + grow * 64 + kq * 4);
      if (RELU) {
        v.x = fmaxf(v.x, 0.f); v.y = fmaxf(v.y, 0.f);
        v.z = fmaxf(v.z, 0.f); v.w = fmaxf(v.w, 0.f);
      }
    }
    xT[kq * 4 + 0][r] = v.x;
    xT[kq * 4 + 1][r] = v.y;
    xT[kq * 4 + 2][r] = v.z;
    xT[kq * 4 + 3][r] = v.w;
  }

  for (int rel = 0; rel < nrel; ++rel) {
    __syncthreads();  // guards xT staging (rel==0) and previous Wl use (rel>0)
    const float* Bp = B + (long)rel * 64 * DOUT;
    for (int idx = tid * 4; idx < 64 * DOUT; idx += 1024) {
      *reinterpret_cast<float4*>(&Wl[idx]) = *reinterpret_cast<const float4*>(Bp + idx);
    }
    __syncthreads();

    if (DOUT == 64) {
      const int rg = tid >> 4, cg = tid & 15;  // 4 rows x 4 cols per thread
      float acc[4][4] = {};
#pragma unroll 16
      for (int k = 0; k < 64; ++k) {
        float4 xv = *reinterpret_cast<const float4*>(&xT[k][rg * 4]);
        float4 wv = *reinterpret_cast<const float4*>(&Wl[k * 64 + cg * 4]);
        acc[0][0] += xv.x * wv.x; acc[0][1] += xv.x * wv.y; acc[0][2] += xv.x * wv.z; acc[0][3] += xv.x * wv.w;
        acc[1][0] += xv.y * wv.x; acc[1][1] += xv.y * wv.y; acc[1][2] += xv.y * wv.z; acc[1][3] += xv.y * wv.w;
        acc[2][0] += xv.z * wv.x; acc[2][1] += xv.z * wv.y; acc[2][2] += xv.z * wv.z; acc[2][3] += xv.z * wv.w;
        acc[3][0] += xv.w * wv.x; acc[3][1] += xv.w * wv.y; acc[3][2] += xv.w * wv.z; acc[3][3] += xv.w * wv.w;
      }
#pragma unroll
      for (int i = 0; i < 4; ++i) {
        long grow = row0 + rg * 4 + i;
        if (grow < (long)NN) {
          float4 o;
          o.x = acc[i][0]; o.y = acc[i][1]; o.z = acc[i][2]; o.w = acc[i][3];
          if (bias) {
            o.x += bias[cg * 4 + 0]; o.y += bias[cg * 4 + 1];
            o.z += bias[cg * 4 + 2]; o.w += bias[cg * 4 + 3];
          }
          *reinterpret_cast<float4*>(OUT + ((long)rel * NN + grow) * 64 + cg * 4) = o;
        }
      }
    } else {  // DOUT == 16: 4 rows x 1 col per thread
      const int rg = tid >> 4, c = tid & 15;
      float acc[4] = {};
#pragma unroll 16
      for (int k = 0; k < 64; ++k) {
        float4 xv = *reinterpret_cast<const float4*>(&xT[k][rg * 4]);
        float w = Wl[k * DOUT + c];
        acc[0] += xv.x * w; acc[1] += xv.y * w; acc[2] += xv.z * w; acc[3] += xv.w * w;
      }
      float bv = bias ? bias[c] : 0.f;
#pragma unroll
      for (int i = 0; i < 4; ++i) {
        long grow = row0 + rg * 4 + i;
        if (grow < (long)NN) OUT[((long)rel * NN + grow) * DOUT + c] = acc[i] + bv;
      }
    }
  }
}

// ---------------- scatter kernel: out[dst] += XR[type][src] / count ----------------
template <int DOUT>
__global__ __launch_bounds__(256) void scatter_k(const int* __restrict__ ei,
                                                 const int* __restrict__ et,
                                                 const unsigned* __restrict__ C,
                                                 const float* __restrict__ XR,
                                                 float* __restrict__ out, int r0,
                                                 int chunk) {
  const int EPW = 64 / DOUT;  // edges per wave
  const int lane = threadIdx.x & 63;
  const int sub = lane / DOUT, d = lane % DOUT;
  long wid = ((long)blockIdx.x * blockDim.x + threadIdx.x) >> 6;
  long nw = ((long)gridDim.x * blockDim.x) >> 6;
  for (long e = wid * EPW + sub; e < EE; e += nw * EPW) {
    int t = et[e];
    if (t < r0 || t >= r0 + chunk) continue;
    int s = ei[e];
    int dd = ei[EE + e];
    unsigned c = C[(long)dd * NREL + t];  // >=1 (this edge exists)
    float rcp = 1.0f / (float)c;
    float v = XR[((long)(t - r0) * NN + s) * DOUT + d] * rcp;
    atomicAdd(&out[(long)dd * DOUT + d], v);
  }
}

// ---------------- sigmoid ----------------
__global__ __launch_bounds__(256) void sigmoid_k(float* __restrict__ out, long n) {
  long i = (long)blockIdx.x * blockDim.x + threadIdx.x;
  long stride = (long)gridDim.x * blockDim.x;
  for (; i < n; i += stride) out[i] = 1.0f / (1.0f + expf(-out[i]));
}

extern "C" void kernel_launch(void* const* d_in, const int* in_sizes, int n_in,
                              void* d_out, int out_size, void* d_ws, size_t ws_size,
                              hipStream_t stream) {
  const int* ei = (const int*)d_in[0];        // [2, E]
  const int* et = (const int*)d_in[1];        // [E]
  const float* emb = (const float*)d_in[2];   // [N, 64]
  const float* W1 = (const float*)d_in[3];    // [16, 64, 64]
  const float* root1 = (const float*)d_in[4]; // [64, 64]
  const float* bias1 = (const float*)d_in[5]; // [64]
  const float* W2 = (const float*)d_in[6];    // [16, 64, 16]
  const float* root2 = (const float*)d_in[7]; // [64, 16]
  const float* bias2 = (const float*)d_in[8]; // [16]
  float* out = (float*)d_out;                 // [N, 16]

  uint8_t* ws = (uint8_t*)d_ws;
  unsigned* C = (unsigned*)ws;                        // 6.4 MB
  float* h1 = (float*)(ws + 6400000);                 // 25.6 MB
  float* XR = (float*)(ws + 32000000);                // chunk * 25.6 MB (L1) / chunk * 6.4 MB (L2)

  long avail = (long)ws_size - 32000000;
  int chunk1 = (int)(avail / 25600000L);
  if (chunk1 < 1) chunk1 = 1;
  if (chunk1 > 16) chunk1 = 16;
  int chunk2 = (int)(avail / 6400000L);
  if (chunk2 < 1) chunk2 = 1;
  if (chunk2 > 16) chunk2 = 16;

  const int nrow_blocks = (NN + 63) / 64;  // 1563

  hipMemsetAsync(C, 0, (size_t)NN * NREL * 4, stream);
  count_k<<<2048, 256, 0, stream>>>(ei, et, C);

  // ---- layer 1 ----
  gemm_k<64, false><<<nrow_blocks, 256, 0, stream>>>(emb, root1, bias1, h1, 1);
  for (int r0 = 0; r0 < NREL; r0 += chunk1) {
    int c = (NREL - r0 < chunk1) ? (NREL - r0) : chunk1;
    gemm_k<64, false><<<nrow_blocks, 256, 0, stream>>>(emb, W1 + (long)r0 * 64 * 64, nullptr, XR, c);
    scatter_k<64><<<4096, 256, 0, stream>>>(ei, et, C, XR, h1, r0, c);
  }

  // ---- layer 2 (relu fused on A loads) ----
  gemm_k<16, true><<<nrow_blocks, 256, 0, stream>>>(h1, root2, bias2, out, 1);
  for (int r0 = 0; r0 < NREL; r0 += chunk2) {
    int c = (NREL - r0 < chunk2) ? (NREL - r0) : chunk2;
    gemm_k<16, true><<<nrow_blocks, 256, 0, stream>>>(h1, W2 + (long)r0 * 64 * 16, nullptr, XR, c);
    scatter_k<16><<<4096, 256, 0, stream>>>(ei, et, C, XR, out, r0, c);
  }

  sigmoid_k<<<6250, 256, 0, stream>>>(out, (long)NN * 16);
}